// Round 5
// baseline (94.163 us; speedup 1.0000x reference)
//
#include <hip/hip_runtime.h>

typedef unsigned short u16;
typedef __attribute__((ext_vector_type(8))) short short8;
typedef __attribute__((ext_vector_type(4))) float f32x4;

typedef void gvoid_t __attribute__((address_space(1)));
typedef void lvoid_t __attribute__((address_space(3)));

#define M_DIM 8192   // B*T
#define N_DIM 1024   // K codebook entries
#define K_DIM 512    // D

__device__ __forceinline__ void async_copy16(const void* g, void* l) {
  __builtin_amdgcn_global_load_lds((gvoid_t*)g, (lvoid_t*)l, 16, 0, 0);
}

__device__ __forceinline__ unsigned bf16bits(float v) {
  union { float f; unsigned u; } c; c.f = v;
  return (c.u + 0x7FFFu + ((c.u >> 16) & 1u)) >> 16;  // RNE
}

// Tiny pre-pass: codebook fp32 -> bf16 + per-row sum of squares (1024 rows).
__global__ __launch_bounds__(256) void cvt_cb_kernel(
    const float* __restrict__ cb, u16* __restrict__ cbb, float* __restrict__ csq) {
  int row = blockIdx.x * 4 + (threadIdx.x >> 6);
  int lane = threadIdx.x & 63;
  const float* src = cb + (size_t)row * K_DIM;
  u16* dst = cbb + (size_t)row * K_DIM;
  const float4* s4 = (const float4*)src;
  float4 v0 = s4[lane];
  float4 v1 = s4[lane + 64];
  float s = v0.x * v0.x + v0.y * v0.y + v0.z * v0.z + v0.w * v0.w +
            v1.x * v1.x + v1.y * v1.y + v1.z * v1.z + v1.w * v1.w;
  uint2* d2 = (uint2*)dst;
  d2[lane]      = make_uint2(bf16bits(v0.x) | (bf16bits(v0.y) << 16),
                             bf16bits(v0.z) | (bf16bits(v0.w) << 16));
  d2[lane + 64] = make_uint2(bf16bits(v1.x) | (bf16bits(v1.y) << 16),
                             bf16bits(v1.z) | (bf16bits(v1.w) << 16));
#pragma unroll
  for (int off = 32; off > 0; off >>= 1) s += __shfl_xor(s, off, 64);
  if (lane == 0) csq[row] = s;
}

// Fused GEMM: converts its OWN A-tile fp32->bf16 during staging (no xb
// round-trip, no serial x-cvt kernel), computes ||x||^2 on the fly.
// B staged async via global_load_lds from pre-converted bf16 codebook.
// Double-buffered LDS, one barrier per K-step, XOR bank swizzle, XCD-aware
// block mapping (per-XCD working set: 2 MB x + 1 MB cbb, L2-resident).
__global__ __launch_bounds__(256) void qgemm_fused(
    const float* __restrict__ X, const u16* __restrict__ Bm,
    const float* __restrict__ csq, const float* __restrict__ prec,
    float* __restrict__ out) {
  __shared__ char lds[65536];     // buf b: A bf16 at b*32768, B at +16384
  __shared__ float xsq_lds[128];
  const int tid = threadIdx.x;
  const int wave = tid >> 6, lane = tid & 63;

  const int lin = blockIdx.x;                // 0..511
  const int xcd = lin & 7;
  const int idx = lin >> 3;
  const int ytile = (xcd << 3) | (idx & 7);  // m-tile (8 per XCD)
  const int xtile = idx >> 3;                // n-tile
  const int m0 = ytile * 128, n0 = xtile * 128;

  const int wm = wave >> 1, wn = wave & 1;   // 2x2 wave grid, 64x64 per wave
  const int ml = lane & 15, q = lane >> 4;
  // B staging (async): 8-row chunks, swizzled 16B col
  const int srow = lane >> 3;
  const int scol = ((lane & 7) ^ srow) * 8;
  // A staging (fp32 load + cvt + ds_write): lane -> row-group row ar, k-chunk ak
  const int ar = lane >> 3;                  // 0..7
  const int ak = lane & 7;                   // 0..7 (16B bf16 chunk index)
  const int apos = (ak ^ ar) * 16;           // swizzled byte pos (row&7 == ar)

  float xsq_acc[4] = {0.f, 0.f, 0.f, 0.f};
  float4 av[8];

  auto loadA = [&](int k0) {
#pragma unroll
    for (int c = 0; c < 4; c++) {
      const float* g = X + (size_t)(m0 + c * 32 + wave * 8 + ar) * K_DIM + k0 + ak * 8;
      av[2 * c]     = ((const float4*)g)[0];
      av[2 * c + 1] = ((const float4*)g)[1];
    }
  };
  auto writeA = [&](int buf) {
    char* base = lds + buf * 32768;
#pragma unroll
    for (int c = 0; c < 4; c++) {
      float4 v0 = av[2 * c], v1 = av[2 * c + 1];
      xsq_acc[c] += v0.x * v0.x + v0.y * v0.y + v0.z * v0.z + v0.w * v0.w +
                    v1.x * v1.x + v1.y * v1.y + v1.z * v1.z + v1.w * v1.w;
      uint4 pk = make_uint4(bf16bits(v0.x) | (bf16bits(v0.y) << 16),
                            bf16bits(v0.z) | (bf16bits(v0.w) << 16),
                            bf16bits(v1.x) | (bf16bits(v1.y) << 16),
                            bf16bits(v1.z) | (bf16bits(v1.w) << 16));
      *(uint4*)(base + (c * 32 + wave * 8 + ar) * 128 + apos) = pk;
    }
  };
  auto stageB = [&](int k0, int buf) {
    char* base = lds + buf * 32768 + 16384;
#pragma unroll
    for (int c = wave; c < 16; c += 4) {
      const u16* gb = Bm + (size_t)(n0 + c * 8 + srow) * K_DIM + (k0 + scol);
      async_copy16(gb, base + c * 1024);
    }
  };

  // Prologue: stage step 0 into buf 0.
  loadA(0);
  stageB(0, 0);
  const float p = prec[0];
  float csv[4];
#pragma unroll
  for (int j = 0; j < 4; j++) csv[j] = csq[n0 + wn * 64 + j * 16 + ml];
  writeA(0);

  f32x4 acc[4][4] = {};
  __syncthreads();  // stage(0) visible (drains vmcnt for B, lgkm for A)

  for (int step = 0; step < 8; step++) {
    if (step < 7) { loadA((step + 1) * 64); stageB((step + 1) * 64, (step + 1) & 1); }
    const char* base = lds + (step & 1) * 32768;
#pragma unroll
    for (int kk = 0; kk < 2; kk++) {
      const int pcol = ((((kk << 2) | q) ^ (lane & 7)) << 4);  // swizzled byte col
      short8 a[4], b[4];
#pragma unroll
      for (int i = 0; i < 4; i++) {
        a[i] = *(const short8*)(base + (wm * 64 + i * 16 + ml) * 128 + pcol);
        b[i] = *(const short8*)(base + 16384 + (wn * 64 + i * 16 + ml) * 128 + pcol);
      }
#pragma unroll
      for (int i = 0; i < 4; i++)
#pragma unroll
        for (int j = 0; j < 4; j++)
          acc[i][j] = __builtin_amdgcn_mfma_f32_16x16x32_bf16(a[i], b[j], acc[i][j], 0, 0, 0);
    }
    if (step < 7) writeA((step + 1) & 1);  // cvt+ds_write hides after MFMA issue
    __syncthreads();
  }

  // ||x||^2: reduce per-lane partials over the 8 k-chunk lanes (ak = 0..7).
#pragma unroll
  for (int c = 0; c < 4; c++) {
    float s = xsq_acc[c];
    s += __shfl_xor(s, 1, 64);
    s += __shfl_xor(s, 2, 64);
    s += __shfl_xor(s, 4, 64);
    if (ak == 0) xsq_lds[c * 32 + wave * 8 + ar] = s;
  }
  __syncthreads();

  // Epilogue: out = p * (2*xc - ||x||^2 - ||c||^2)
  // C/D layout: col = lane&15, row = (lane>>4)*4 + reg  [m89-verified]
#pragma unroll
  for (int i = 0; i < 4; i++) {
#pragma unroll
    for (int r = 0; r < 4; r++) {
      int lrow = wm * 64 + i * 16 + q * 4 + r;
      float xs = xsq_lds[lrow];
      float* orow = out + (size_t)(m0 + lrow) * N_DIM + n0 + wn * 64 + ml;
#pragma unroll
      for (int j = 0; j < 4; j++)
        __builtin_nontemporal_store(p * (2.0f * acc[i][j][r] - xs - csv[j]),
                                    orow + j * 16);
    }
  }
}

extern "C" void kernel_launch(void* const* d_in, const int* in_sizes, int n_in,
                              void* d_out, int out_size, void* d_ws, size_t ws_size,
                              hipStream_t stream) {
  const float* x    = (const float*)d_in[0];   // [8,1024,512] fp32
  const float* cb   = (const float*)d_in[1];   // [1024,512] fp32
  const float* prec = (const float*)d_in[2];   // [1] fp32
  float* out = (float*)d_out;                  // [8,1024,1024] fp32

  char* ws = (char*)d_ws;
  u16*   cbb = (u16*)(ws);                      // 1 MiB bf16 codebook
  float* csq = (float*)(ws + 1048576);          // 4 KiB

  cvt_cb_kernel<<<256, 256, 0, stream>>>(cb, cbb, csq);
  qgemm_fused<<<512, 256, 0, stream>>>(x, cbb, csq, prec, out);
}

// Round 6
// 90.619 us; speedup vs baseline: 1.0391x; 1.0391x over previous
//
#include <hip/hip_runtime.h>

typedef unsigned short u16;
typedef __attribute__((ext_vector_type(8))) short short8;
typedef __attribute__((ext_vector_type(4))) float f32x4;

typedef void gvoid_t __attribute__((address_space(1)));
typedef void lvoid_t __attribute__((address_space(3)));

#define M_DIM 8192   // B*T
#define N_DIM 1024   // K codebook entries
#define K_DIM 512    // D

__device__ __forceinline__ void async_copy16(const void* g, void* l) {
  // lane i's 16B land at (wave-uniform l) + i*16.
  __builtin_amdgcn_global_load_lds((gvoid_t*)g, (lvoid_t*)l, 16, 0, 0);
}

__device__ __forceinline__ unsigned bf16bits(float v) {
  union { float f; unsigned u; } c; c.f = v;
  return (c.u + 0x7FFFu + ((c.u >> 16) & 1u)) >> 16;  // RNE
}

// Pass 1: fp32 -> bf16 convert + per-row sum of squares. One wave per row.
// Coalesced: lane i loads float4[lane] and float4[lane+64].
// NOTE (R5 post-mortem): fusing this into the GEMM regressed 91.2->94.2 us —
// fp32 A-loads + VALU cvt + ds_write on the K-loop critical path beat the
// async global_load_lds DMA path. Keep the two-pass structure.
__global__ __launch_bounds__(256) void cvt_sq_kernel(
    const float* __restrict__ x, const float* __restrict__ cb,
    u16* __restrict__ xb, u16* __restrict__ cbb,
    float* __restrict__ xsq, float* __restrict__ csq) {
  int row = blockIdx.x * 4 + (threadIdx.x >> 6);
  int lane = threadIdx.x & 63;
  const float* src; u16* dst; float* sq;
  if (row < M_DIM) {
    src = x + (size_t)row * K_DIM; dst = xb + (size_t)row * K_DIM; sq = xsq + row;
  } else {
    int r = row - M_DIM;
    src = cb + (size_t)r * K_DIM; dst = cbb + (size_t)r * K_DIM; sq = csq + r;
  }
  const float4* s4 = (const float4*)src;
  float4 v0 = s4[lane];
  float4 v1 = s4[lane + 64];
  float s = v0.x * v0.x + v0.y * v0.y + v0.z * v0.z + v0.w * v0.w +
            v1.x * v1.x + v1.y * v1.y + v1.z * v1.z + v1.w * v1.w;
  uint2* d2 = (uint2*)dst;
  d2[lane]      = make_uint2(bf16bits(v0.x) | (bf16bits(v0.y) << 16),
                             bf16bits(v0.z) | (bf16bits(v0.w) << 16));
  d2[lane + 64] = make_uint2(bf16bits(v1.x) | (bf16bits(v1.y) << 16),
                             bf16bits(v1.z) | (bf16bits(v1.w) << 16));
#pragma unroll
  for (int off = 32; off > 0; off >>= 1) s += __shfl_xor(s, off, 64);
  if (lane == 0) *sq = s;
}

// Pass 2: 128x128 MFMA GEMM (bf16, B^T layout) + distance epilogue.
// Best-measured config (R3, 91.2 us): double-buffered LDS, one barrier per
// K-step, XOR bank swizzle (R4 A/B: removal was weakly negative), XCD-aware
// block mapping (per-XCD working set 1 MB A + 1 MB codebook, L2-resident).
__global__ __launch_bounds__(256) void qgemm_kernel(
    const u16* __restrict__ A, const u16* __restrict__ B,
    const float* __restrict__ xsq, const float* __restrict__ csq,
    const float* __restrict__ prec, float* __restrict__ out) {
  __shared__ char lds[65536];  // buf b: A at b*32768, B at b*32768+16384
  const int tid = threadIdx.x;
  const int wave = tid >> 6, lane = tid & 63;

  const int lin = blockIdx.x;          // 0..511
  const int xcd = lin & 7;
  const int idx = lin >> 3;            // 0..63
  const int ytile = (xcd << 3) | (idx & 7);  // m-tile 0..63 (8 per XCD)
  const int xtile = idx >> 3;                // n-tile 0..7
  const int m0 = ytile * 128, n0 = xtile * 128;

  const int wm = wave >> 1, wn = wave & 1;   // 2x2 wave grid, 64x64 per wave
  const int srow = lane >> 3;                 // row within 8-row staging chunk
  const int scol = ((lane & 7) ^ srow) * 8;   // swizzled k-element offset
  const int ml = lane & 15, q = lane >> 4;

  auto stage = [&](int k0, int buf) {
    char* base = lds + buf * 32768;
#pragma unroll
    for (int c = wave; c < 16; c += 4) {
      const u16* ga = A + (size_t)(m0 + c * 8 + srow) * K_DIM + (k0 + scol);
      async_copy16(ga, base + c * 1024);
      const u16* gb = B + (size_t)(n0 + c * 8 + srow) * K_DIM + (k0 + scol);
      async_copy16(gb, base + 16384 + c * 1024);
    }
  };

  stage(0, 0);

  // Pre-load epilogue operands (latency hidden under the K-loop).
  const float p = prec[0];
  float csv[4];
#pragma unroll
  for (int j = 0; j < 4; j++) csv[j] = csq[n0 + wn * 64 + j * 16 + ml];

  f32x4 acc[4][4] = {};
  __syncthreads();  // stage(0) visible

  for (int step = 0; step < 8; step++) {
    if (step < 7) stage((step + 1) * 64, (step + 1) & 1);
    const char* base = lds + (step & 1) * 32768;
#pragma unroll
    for (int kk = 0; kk < 2; kk++) {
      const int pcol = ((((kk << 2) | q) ^ (lane & 7)) << 4);  // swizzled byte col
      short8 a[4], b[4];
#pragma unroll
      for (int i = 0; i < 4; i++) {
        a[i] = *(const short8*)(base + (wm * 64 + i * 16 + ml) * 128 + pcol);
        b[i] = *(const short8*)(base + 16384 + (wn * 64 + i * 16 + ml) * 128 + pcol);
      }
#pragma unroll
      for (int i = 0; i < 4; i++)
#pragma unroll
        for (int j = 0; j < 4; j++)
          acc[i][j] = __builtin_amdgcn_mfma_f32_16x16x32_bf16(a[i], b[j], acc[i][j], 0, 0, 0);
    }
    __syncthreads();  // drains stage(step+1); protects buf (reuse distance 2)
  }

  // Epilogue: out = p * (2*xc - ||x||^2 - ||c||^2)
  // C/D layout: col = lane&15, row = (lane>>4)*4 + reg  [m89-verified]
#pragma unroll
  for (int i = 0; i < 4; i++) {
#pragma unroll
    for (int r = 0; r < 4; r++) {
      int row = m0 + wm * 64 + i * 16 + q * 4 + r;
      float xs = xsq[row];
      float* orow = out + (size_t)row * N_DIM + n0 + wn * 64 + ml;
#pragma unroll
      for (int j = 0; j < 4; j++)
        __builtin_nontemporal_store(p * (2.0f * acc[i][j][r] - xs - csv[j]),
                                    orow + j * 16);
    }
  }
}

extern "C" void kernel_launch(void* const* d_in, const int* in_sizes, int n_in,
                              void* d_out, int out_size, void* d_ws, size_t ws_size,
                              hipStream_t stream) {
  const float* x    = (const float*)d_in[0];   // [8,1024,512] fp32
  const float* cb   = (const float*)d_in[1];   // [1024,512] fp32
  const float* prec = (const float*)d_in[2];   // [1] fp32
  float* out = (float*)d_out;                  // [8,1024,1024] fp32

  char* ws = (char*)d_ws;
  u16*   xb  = (u16*)(ws);                      // 8 MiB bf16 x
  u16*   cbb = (u16*)(ws + 8388608);            // 1 MiB bf16 codebook
  float* xsq = (float*)(ws + 9437184);          // 32 KiB
  float* csq = (float*)(ws + 9469952);          // 4 KiB

  cvt_sq_kernel<<<2304, 256, 0, stream>>>(x, cb, xb, cbb, xsq, csq);
  qgemm_kernel<<<512, 256, 0, stream>>>(xb, cbb, xsq, csq, prec, out);
}